// Round 22
// baseline (181.900 us; speedup 1.0000x reference)
//
#include <hip/hip_runtime.h>
#include <stdint.h>

#define G_ 8
#define S_ 16
#define H_ 512
#define TB 64
#define NTH 256

typedef _Float16 h16;
typedef _Float16 h16x8 __attribute__((ext_vector_type(8)));
typedef float f32x4 __attribute__((ext_vector_type(4)));
typedef float f32x16 __attribute__((ext_vector_type(16)));

#define HB_BYTES (TB * 1024)              // 64 rows x 512 h16 = 64 KB (k-major)
#define XB_BYTES 2048                     // 64 rows x 16 h16 (k-major)
#define SMEM_BYTES (HB_BYTES + XB_BYTES)  // 66 KB -> 2 blocks/CU

// K-MAJOR activation layout: element (row b, chan c) at byte
//   (c>>3)*1024 + b*16 + (c&7)*2  -> contiguous 512B runs, conflict-free,
// one base register + compile-time immediate offsets.
//
// GEOMETRY (r21 best, 181us): 4 waves/block, wave = 128 o-cols x 64 b-rows,
// acc = 128 VGPR, __launch_bounds__(256,2), 2 blocks/CU.
// r22: DEPTH-4 A-pipeline. Per-XCD L2 runs at ~74% utilization -> queueing
// inflates load latency to ~800-1000 cyc; depth-2 (~512 matrix-cyc) was
// insufficient. Four named frag sets (aA..aD, rotation-free), each consumed
// at step i and refilled for step i+4: loads lead consumers by ~1024+ cyc.
// Registers: acc 128 + frags 64 + misc ~25 ~= 220 < 256 budget.

__device__ __forceinline__ float swishf(float v, float spl) {
    const float e = __builtin_amdgcn_exp2f(__builtin_fmaf(-spl, v, 0.13750352f));
    return v * __builtin_amdgcn_rcpf(1.1f + e);
}

__device__ __forceinline__ uint32_t pk16(float a, float b) {
    return __builtin_bit_cast(uint32_t, __builtin_amdgcn_cvt_pkrtz(a, b));
}

// ---- A-operand (weight) fragment loaders ----
// 32x32x16 frag, ks-major packed layout [ks][nb=0..15][64][8]:
// lane ln: m-row = nb*32 + (ln&31), k = ks*16 + (ln>>5)*8 + j.
template<bool USEWS>
__device__ __forceinline__ h16x8 loadA32ks(const h16* __restrict__ wpk,
                                           const float* __restrict__ wf,
                                           int ks, int nb, int ln, int Ksrc) {
    if constexpr (USEWS) {
        return *(const h16x8*)(wpk + (((size_t)ks * 16 + nb) * 64 + ln) * 8);
    } else {
        const int row = nb * 32 + (ln & 31);
        const int k = ks * 16 + (ln >> 5) * 8;
        const float* p = wf + (size_t)row * Ksrc + k;
        h16x8 r;
        #pragma unroll
        for (int j = 0; j < 8; ++j) r[j] = (h16)p[j];
        return r;
    }
}

// 16x16x32 frag (W4): lane ln: m-row = ln&15, k = ks32*32 + (ln>>4)*8 + j
template<bool USEWS>
__device__ __forceinline__ h16x8 loadA16(const h16* __restrict__ wpk,
                                         const float* __restrict__ wf,
                                         int ks32, int ln, int Ksrc) {
    if constexpr (USEWS) {
        return *(const h16x8*)(wpk + ((size_t)ks32 * 64 + ln) * 8);
    } else {
        const int row = ln & 15;
        const int k = ks32 * 32 + (ln >> 4) * 8;
        const float* p = wf + (size_t)row * Ksrc + k;
        h16x8 r;
        #pragma unroll
        for (int j = 0; j < 8; ++j) r[j] = (h16)p[j];
        return r;
    }
}

// D (32x32): lane&31 = batch row (within bt 32-row half); o-row =
// (reg&3)+8*(reg>>2)+4*(lane>>5). 4 consecutive o per reg-quad = 8 contiguous
// bytes in k-major LDS. Wave wv owns cols [128wv, 128wv+128).
__device__ __forceinline__ void swish_store32(const f32x16 (&acc)[4][2], char* hb,
                                              const float* __restrict__ bias, float spl,
                                              int wv, int ln) {
    const int l31 = ln & 31, lh = ln >> 5;
    char* const wbase = hb + wv * 16384 + l31 * 16 + lh * 8;
    #pragma unroll
    for (int ot = 0; ot < 4; ++ot) {
        #pragma unroll
        for (int rq = 0; rq < 4; ++rq) {
            const int col0 = wv * 128 + ot * 32 + rq * 8 + lh * 4;
            const f32x4 bv = *(const f32x4*)(bias + col0);
            #pragma unroll
            for (int bt = 0; bt < 2; ++bt) {
                const float v0 = swishf(acc[ot][bt][rq * 4 + 0] + bv[0], spl);
                const float v1 = swishf(acc[ot][bt][rq * 4 + 1] + bv[1], spl);
                const float v2 = swishf(acc[ot][bt][rq * 4 + 2] + bv[2], spl);
                const float v3 = swishf(acc[ot][bt][rq * 4 + 3] + bv[3], spl);
                const uint64_t u = (uint64_t)pk16(v0, v1)
                                 | ((uint64_t)pk16(v2, v3) << 32);
                *(uint64_t*)(wbase + (ot * 4 + rq) * 1024 + bt * 512) = u;
            }
        }
    }
}

// One H->H layer: wave tile 128 o-cols x 64 b-rows, 32x32x16 MFMA, K=512.
// Depth-4 rotation-free pipeline: step i consumes set i&3, then refills that
// set for step i+4 (WAR-ordered after the MFMAs). aP seeds ks=0.
template<bool USEWS>
__device__ __forceinline__ void layerH32(f32x16 (&acc)[4][2], const h16x8 (&aP)[4],
                                         const h16* __restrict__ wpk, const float* __restrict__ wf,
                                         const char* __restrict__ hb, int wv, int ln) {
    const int l31 = ln & 31, lh = ln >> 5;
    const char* const bbase = hb + l31 * 16 + lh * 1024;
    const int nb0 = wv * 4;
    #pragma unroll
    for (int ot = 0; ot < 4; ++ot)
        #pragma unroll
        for (int bt = 0; bt < 2; ++bt) acc[ot][bt] = (f32x16)(0.f);

    h16x8 aA[4], aB[4], aC[4], aD[4];
    #pragma unroll
    for (int ot = 0; ot < 4; ++ot) aA[ot] = aP[ot];
    #pragma unroll
    for (int ot = 0; ot < 4; ++ot) aB[ot] = loadA32ks<USEWS>(wpk, wf, 1, nb0 + ot, ln, H_);
    #pragma unroll
    for (int ot = 0; ot < 4; ++ot) aC[ot] = loadA32ks<USEWS>(wpk, wf, 2, nb0 + ot, ln, H_);
    #pragma unroll
    for (int ot = 0; ot < 4; ++ot) aD[ot] = loadA32ks<USEWS>(wpk, wf, 3, nb0 + ot, ln, H_);

    #pragma unroll 2
    for (int ks = 0; ks < 32; ks += 4) {
        // step ks: consume aA, refill for ks+4
        {
            const h16x8 b0 = *(const h16x8*)(bbase + ks * 2048);
            const h16x8 b1 = *(const h16x8*)(bbase + ks * 2048 + 512);
            __builtin_amdgcn_s_setprio(1);
            #pragma unroll
            for (int ot = 0; ot < 4; ++ot) {
                acc[ot][0] = __builtin_amdgcn_mfma_f32_32x32x16_f16(aA[ot], b0, acc[ot][0], 0, 0, 0);
                acc[ot][1] = __builtin_amdgcn_mfma_f32_32x32x16_f16(aA[ot], b1, acc[ot][1], 0, 0, 0);
            }
            __builtin_amdgcn_s_setprio(0);
            const int ksn = (ks + 4 < 32) ? ks + 4 : 0;
            #pragma unroll
            for (int ot = 0; ot < 4; ++ot)
                aA[ot] = loadA32ks<USEWS>(wpk, wf, ksn, nb0 + ot, ln, H_);
        }
        // step ks+1: consume aB, refill for ks+5
        {
            const h16x8 b0 = *(const h16x8*)(bbase + (ks + 1) * 2048);
            const h16x8 b1 = *(const h16x8*)(bbase + (ks + 1) * 2048 + 512);
            __builtin_amdgcn_s_setprio(1);
            #pragma unroll
            for (int ot = 0; ot < 4; ++ot) {
                acc[ot][0] = __builtin_amdgcn_mfma_f32_32x32x16_f16(aB[ot], b0, acc[ot][0], 0, 0, 0);
                acc[ot][1] = __builtin_amdgcn_mfma_f32_32x32x16_f16(aB[ot], b1, acc[ot][1], 0, 0, 0);
            }
            __builtin_amdgcn_s_setprio(0);
            const int ksn = (ks + 5 < 32) ? ks + 5 : 0;
            #pragma unroll
            for (int ot = 0; ot < 4; ++ot)
                aB[ot] = loadA32ks<USEWS>(wpk, wf, ksn, nb0 + ot, ln, H_);
        }
        // step ks+2: consume aC, refill for ks+6
        {
            const h16x8 b0 = *(const h16x8*)(bbase + (ks + 2) * 2048);
            const h16x8 b1 = *(const h16x8*)(bbase + (ks + 2) * 2048 + 512);
            __builtin_amdgcn_s_setprio(1);
            #pragma unroll
            for (int ot = 0; ot < 4; ++ot) {
                acc[ot][0] = __builtin_amdgcn_mfma_f32_32x32x16_f16(aC[ot], b0, acc[ot][0], 0, 0, 0);
                acc[ot][1] = __builtin_amdgcn_mfma_f32_32x32x16_f16(aC[ot], b1, acc[ot][1], 0, 0, 0);
            }
            __builtin_amdgcn_s_setprio(0);
            const int ksn = (ks + 6 < 32) ? ks + 6 : 0;
            #pragma unroll
            for (int ot = 0; ot < 4; ++ot)
                aC[ot] = loadA32ks<USEWS>(wpk, wf, ksn, nb0 + ot, ln, H_);
        }
        // step ks+3: consume aD, refill for ks+7
        {
            const h16x8 b0 = *(const h16x8*)(bbase + (ks + 3) * 2048);
            const h16x8 b1 = *(const h16x8*)(bbase + (ks + 3) * 2048 + 512);
            __builtin_amdgcn_s_setprio(1);
            #pragma unroll
            for (int ot = 0; ot < 4; ++ot) {
                acc[ot][0] = __builtin_amdgcn_mfma_f32_32x32x16_f16(aD[ot], b0, acc[ot][0], 0, 0, 0);
                acc[ot][1] = __builtin_amdgcn_mfma_f32_32x32x16_f16(aD[ot], b1, acc[ot][1], 0, 0, 0);
            }
            __builtin_amdgcn_s_setprio(0);
            const int ksn = (ks + 7 < 32) ? ks + 7 : 0;
            #pragma unroll
            for (int ot = 0; ot < 4; ++ot)
                aD[ot] = loadA32ks<USEWS>(wpk, wf, ksn, nb0 + ot, ln, H_);
        }
    }
}

template<bool USEWS>
__device__ __forceinline__ void prefA(h16x8 (&aP)[4],
                                      const h16* __restrict__ wpk, const float* __restrict__ wf,
                                      int wv, int ln) {
    #pragma unroll
    for (int ot = 0; ot < 4; ++ot)
        aP[ot] = loadA32ks<USEWS>(wpk, wf, 0, wv * 4 + ot, ln, H_);
}

template<bool USEWS>
__global__ __launch_bounds__(NTH, 2) void mlp_fused(
    const float* __restrict__ x,
    const float* __restrict__ W1f, const float* __restrict__ b1, const float* __restrict__ be1,
    const float* __restrict__ W2f, const float* __restrict__ b2, const float* __restrict__ be2,
    const float* __restrict__ W3f, const float* __restrict__ b3, const float* __restrict__ be3,
    const float* __restrict__ W4f, const float* __restrict__ b4,
    const h16* __restrict__ W1p, const h16* __restrict__ W2p,
    const h16* __restrict__ W3p, const h16* __restrict__ W4p,
    float* __restrict__ out) {
    extern __shared__ char smem[];
    char* __restrict__ xb = smem + HB_BYTES;   // k-major x tile, 2 KB

    const int bid = blockIdx.x;
    const int g = bid & 7;                 // group == XCD; co-resident blocks share weights in L2
    const int rowbase = (bid >> 3) * TB;
    const int tid = threadIdx.x;
    const int wv = tid >> 6;               // 4 waves, wave wv owns cols 128wv..128wv+128
    const int ln = tid & 63;
    const int l31 = ln & 31;
    const int lh = ln >> 5;

    // spl = softplus(beta) * log2(e); swish folds /1.1 into the rcp argument.
    const float spl1 = log1pf(__expf(be1[g])) * 1.44269504f;
    const float spl2 = log1pf(__expf(be2[g])) * 1.44269504f;
    const float spl3 = log1pf(__expf(be3[g])) * 1.44269504f;

    const h16* w1p = W1p + (size_t)g * H_ * S_;
    const h16* w2p = W2p + (size_t)g * H_ * H_;
    const h16* w3p = W3p + (size_t)g * H_ * H_;
    const h16* w4p = W4p + (size_t)g * S_ * H_;
    const float* w1f = W1f + (size_t)g * H_ * S_;
    const float* w2f = W2f + (size_t)g * H_ * H_;
    const float* w3f = W3f + (size_t)g * H_ * H_;
    const float* w4f = W4f + (size_t)g * S_ * H_;

    // stage x tile -> fp16, k-major: (row r, chan s) -> (s>>3)*1024 + r*16 + (s&7)*2
    {
        const int idx = tid * 4;                         // 64*16 = 1024 h16, 4/thread
        const int r = idx >> 4, s = idx & 15;            // s in {0,4,8,12}
        const f32x4 v = *(const f32x4*)(x + (size_t)(rowbase + r) * (G_ * S_) + g * S_ + s);
        const uint64_t u = (uint64_t)pk16(v[0], v[1]) | ((uint64_t)pk16(v[2], v[3]) << 32);
        *(uint64_t*)(xb + (s >> 3) * 1024 + r * 16 + (s & 7) * 2) = u;
    }
    __syncthreads();

    f32x16 acc[4][2];
    h16x8 aP[4];

    // ---- layer 1: A=W1[512,16] frags, B=x frags (k-major), single K-step ----
    {
        #pragma unroll
        for (int ot = 0; ot < 4; ++ot)
            #pragma unroll
            for (int bt = 0; bt < 2; ++bt) acc[ot][bt] = (f32x16)(0.f);
        const char* const xbase = xb + l31 * 16 + lh * 1024;
        const h16x8 bX0 = *(const h16x8*)(xbase);
        const h16x8 bX1 = *(const h16x8*)(xbase + 512);
        #pragma unroll
        for (int ot = 0; ot < 4; ++ot) {
            const h16x8 aW = loadA32ks<USEWS>(w1p, w1f, 0, wv * 4 + ot, ln, S_);
            acc[ot][0] = __builtin_amdgcn_mfma_f32_32x32x16_f16(aW, bX0, acc[ot][0], 0, 0, 0);
            acc[ot][1] = __builtin_amdgcn_mfma_f32_32x32x16_f16(aW, bX1, acc[ot][1], 0, 0, 0);
        }
    }
    prefA<USEWS>(aP, w2p, w2f, wv, ln);    // layer-2 ks=0 frags: latency hides under store
    swish_store32(acc, smem, b1 + g * H_, spl1, wv, ln);
    __syncthreads();

    // ---- layer 2 ----
    layerH32<USEWS>(acc, aP, w2p, w2f, smem, wv, ln);
    __syncthreads();                       // all hbuf reads done
    prefA<USEWS>(aP, w3p, w3f, wv, ln);    // layer-3 ks=0 frags
    swish_store32(acc, smem, b2 + g * H_, spl2, wv, ln);
    __syncthreads();

    // ---- layer 3 ----
    layerH32<USEWS>(acc, aP, w3p, w3f, smem, wv, ln);
    __syncthreads();
    swish_store32(acc, smem, b3 + g * H_, spl3, wv, ln);
    __syncthreads();

    // ---- layer 4: A=W4[16,512] frags (16x16x32), B=act k-major; 4 waves x 16 rows ----
    {
        f32x4 a4 = {0.f, 0.f, 0.f, 0.f};
        const int l15 = ln & 15, lq = ln >> 4;
        // B-frag: row = wv*16+l15, k = ks*32 + lq*8 -> byte = (ks*4+lq)*1024 + row*16
        const char* const b4base = smem + lq * 1024 + (wv * 16 + l15) * 16;
        #pragma unroll 4
        for (int ks = 0; ks < 16; ++ks) {
            const h16x8 a = loadA16<USEWS>(w4p, w4f, ks, ln, H_);
            const h16x8 b = *(const h16x8*)(b4base + ks * 4096);
            a4 = __builtin_amdgcn_mfma_f32_16x16x32_f16(a, b, a4, 0, 0, 0);
        }
        const int brow = wv * 16 + l15;    // batch row
        const int s0 = lq * 4;             // 4 consecutive state channels
        const f32x4 bv = *(const f32x4*)(b4 + g * S_ + s0);
        f32x4 o4;
        #pragma unroll
        for (int r = 0; r < 4; ++r) o4[r] = a4[r] + bv[r];
        *(f32x4*)(out + (size_t)(rowbase + brow) * (G_ * S_) + g * S_ + s0) = o4;
    }
}

// ---- weight repack (32x32x16, ks-major): fp32 [G*N][Ks] -> per-group [ks][nb][64][8] ----
__global__ void packW32(const float* __restrict__ s, h16* __restrict__ d,
                        int KB, int Ks) {
    const int t = blockIdx.x * 256 + threadIdx.x;
    const int total = G_ * KB * 16 * 64;
    if (t >= total) return;
    const int ln = t & 63;
    const int blk = t >> 6;                // ((g*KB + ks)*16 + nb)
    const int nb = blk & 15;
    const int rest = blk >> 4;
    const int ks = rest % KB;
    const int g = rest / KB;
    const int row = g * H_ + nb * 32 + (ln & 31);
    const int k = ks * 16 + (ln >> 5) * 8;
    const float* p = s + (size_t)row * Ks + k;
    h16x8 o;
    #pragma unroll
    for (int j = 0; j < 8; ++j) o[j] = (h16)p[j];
    *(h16x8*)(d + (size_t)t * 8) = o;
}

// ---- weight repack (16x16x32, W4): fp32 [G*16][512] -> per-group [ks][64][8] ----
__global__ void packW16(const float* __restrict__ s, h16* __restrict__ d,
                        int NB_total, int KB, int Ks) {
    const int t = blockIdx.x * 256 + threadIdx.x;
    const int total = NB_total * KB * 64;
    if (t >= total) return;
    const int ln = t & 63;
    const int blk = t >> 6;
    const int kb = blk % KB;
    const int nbg = blk / KB;
    const int row = nbg * 16 + (ln & 15);
    const int k = kb * 32 + (ln >> 4) * 8;
    const float* p = s + (size_t)row * Ks + k;
    h16x8 o;
    #pragma unroll
    for (int j = 0; j < 8; ++j) o[j] = (h16)p[j];
    *(h16x8*)(d + (size_t)t * 8) = o;
}

extern "C" void kernel_launch(void* const* d_in, const int* in_sizes, int n_in,
                              void* d_out, int out_size, void* d_ws, size_t ws_size,
                              hipStream_t stream) {
    const float* x   = (const float*)d_in[0];
    const float* W1  = (const float*)d_in[1];
    const float* b1  = (const float*)d_in[2];
    const float* be1 = (const float*)d_in[3];
    const float* W2  = (const float*)d_in[4];
    const float* b2  = (const float*)d_in[5];
    const float* be2 = (const float*)d_in[6];
    const float* W3  = (const float*)d_in[7];
    const float* b3  = (const float*)d_in[8];
    const float* be3 = (const float*)d_in[9];
    const float* W4  = (const float*)d_in[10];
    const float* b4  = (const float*)d_in[11];
    float* out = (float*)d_out;

    const size_t nW2  = (size_t)G_ * H_ * H_;   // 2097152
    const size_t nW1p = (size_t)G_ * H_ * S_;   // 65536
    const size_t nW4  = (size_t)G_ * S_ * H_;   // 65536
    const size_t need = (2 * nW2 + nW1p + nW4) * sizeof(h16);

    const dim3 grid((16384 / TB) * G_), blk(NTH);   // 2048 blocks x 256 thr

    if (ws_size >= need) {
        h16* W2p = (h16*)d_ws;
        h16* W3p = W2p + nW2;
        h16* W1p = W3p + nW2;
        h16* W4p = W1p + nW1p;
        packW32<<<dim3((unsigned)((nW2 / 8 + 255) / 256)), dim3(256), 0, stream>>>(W2, W2p, 32, H_);
        packW32<<<dim3((unsigned)((nW2 / 8 + 255) / 256)), dim3(256), 0, stream>>>(W3, W3p, 32, H_);
        packW32<<<dim3((unsigned)((nW1p / 8 + 255) / 256)), dim3(256), 0, stream>>>(W1, W1p, 1, S_);
        packW16<<<dim3((unsigned)((nW4 / 8 + 255) / 256)), dim3(256), 0, stream>>>(W4, W4p, G_, 16, H_);
        (void)hipFuncSetAttribute(reinterpret_cast<const void*>(mlp_fused<true>),
                                  hipFuncAttributeMaxDynamicSharedMemorySize, (int)SMEM_BYTES);
        mlp_fused<true><<<grid, blk, SMEM_BYTES, stream>>>(
            x, W1, b1, be1, W2, b2, be2, W3, b3, be3, W4, b4,
            W1p, W2p, W3p, W4p, out);
    } else {
        (void)hipFuncSetAttribute(reinterpret_cast<const void*>(mlp_fused<false>),
                                  hipFuncAttributeMaxDynamicSharedMemorySize, (int)SMEM_BYTES);
        mlp_fused<false><<<grid, blk, SMEM_BYTES, stream>>>(
            x, W1, b1, be1, W2, b2, be2, W3, b3, be3, W4, b4,
            nullptr, nullptr, nullptr, nullptr, out);
    }
}

// Round 23
// 181.082 us; speedup vs baseline: 1.0045x; 1.0045x over previous
//
#include <hip/hip_runtime.h>
#include <stdint.h>

#define G_ 8
#define S_ 16
#define H_ 512
#define TB 64
#define NTH 256

typedef _Float16 h16;
typedef _Float16 h16x8 __attribute__((ext_vector_type(8)));
typedef float f32x4 __attribute__((ext_vector_type(4)));
typedef float f32x16 __attribute__((ext_vector_type(16)));

#define HB_BYTES (TB * 1024)              // 64 rows x 512 h16 = 64 KB (k-major)
#define XB_BYTES 2048                     // 64 rows x 16 h16 (k-major)
#define SMEM_BYTES (HB_BYTES + XB_BYTES)  // 66 KB -> 2 blocks/CU

// K-MAJOR activation layout: element (row b, chan c) at byte
//   (c>>3)*1024 + b*16 + (c&7)*2  -> contiguous 512B runs, conflict-free,
// one base register + compile-time immediate offsets.
//
// FINAL (r21 optimum, 181.5us measured): 4 waves/block, wave = 128 o-cols x
// 64 b-rows, acc = 128 VGPR, __launch_bounds__(256,2), 2 blocks/CU,
// rotation-free depth-2 A-pipeline (even/odd named sets, zero v_movs),
// slim swish (exp2-folded), cross-barrier prefA seeding.
// Depth-4 (r22) measured null; flags/stagger (r12/r16/r17) null-to-negative.

__device__ __forceinline__ float swishf(float v, float spl) {
    const float e = __builtin_amdgcn_exp2f(__builtin_fmaf(-spl, v, 0.13750352f));
    return v * __builtin_amdgcn_rcpf(1.1f + e);
}

__device__ __forceinline__ uint32_t pk16(float a, float b) {
    return __builtin_bit_cast(uint32_t, __builtin_amdgcn_cvt_pkrtz(a, b));
}

// ---- A-operand (weight) fragment loaders ----
// 32x32x16 frag, ks-major packed layout [ks][nb=0..15][64][8]:
// lane ln: m-row = nb*32 + (ln&31), k = ks*16 + (ln>>5)*8 + j.
template<bool USEWS>
__device__ __forceinline__ h16x8 loadA32ks(const h16* __restrict__ wpk,
                                           const float* __restrict__ wf,
                                           int ks, int nb, int ln, int Ksrc) {
    if constexpr (USEWS) {
        return *(const h16x8*)(wpk + (((size_t)ks * 16 + nb) * 64 + ln) * 8);
    } else {
        const int row = nb * 32 + (ln & 31);
        const int k = ks * 16 + (ln >> 5) * 8;
        const float* p = wf + (size_t)row * Ksrc + k;
        h16x8 r;
        #pragma unroll
        for (int j = 0; j < 8; ++j) r[j] = (h16)p[j];
        return r;
    }
}

// 16x16x32 frag (W4): lane ln: m-row = ln&15, k = ks32*32 + (ln>>4)*8 + j
template<bool USEWS>
__device__ __forceinline__ h16x8 loadA16(const h16* __restrict__ wpk,
                                         const float* __restrict__ wf,
                                         int ks32, int ln, int Ksrc) {
    if constexpr (USEWS) {
        return *(const h16x8*)(wpk + ((size_t)ks32 * 64 + ln) * 8);
    } else {
        const int row = ln & 15;
        const int k = ks32 * 32 + (ln >> 4) * 8;
        const float* p = wf + (size_t)row * Ksrc + k;
        h16x8 r;
        #pragma unroll
        for (int j = 0; j < 8; ++j) r[j] = (h16)p[j];
        return r;
    }
}

// D (32x32): lane&31 = batch row (within bt 32-row half); o-row =
// (reg&3)+8*(reg>>2)+4*(lane>>5). 4 consecutive o per reg-quad = 8 contiguous
// bytes in k-major LDS. Wave wv owns cols [128wv, 128wv+128).
__device__ __forceinline__ void swish_store32(const f32x16 (&acc)[4][2], char* hb,
                                              const float* __restrict__ bias, float spl,
                                              int wv, int ln) {
    const int l31 = ln & 31, lh = ln >> 5;
    char* const wbase = hb + wv * 16384 + l31 * 16 + lh * 8;
    #pragma unroll
    for (int ot = 0; ot < 4; ++ot) {
        #pragma unroll
        for (int rq = 0; rq < 4; ++rq) {
            const int col0 = wv * 128 + ot * 32 + rq * 8 + lh * 4;
            const f32x4 bv = *(const f32x4*)(bias + col0);
            #pragma unroll
            for (int bt = 0; bt < 2; ++bt) {
                const float v0 = swishf(acc[ot][bt][rq * 4 + 0] + bv[0], spl);
                const float v1 = swishf(acc[ot][bt][rq * 4 + 1] + bv[1], spl);
                const float v2 = swishf(acc[ot][bt][rq * 4 + 2] + bv[2], spl);
                const float v3 = swishf(acc[ot][bt][rq * 4 + 3] + bv[3], spl);
                const uint64_t u = (uint64_t)pk16(v0, v1)
                                 | ((uint64_t)pk16(v2, v3) << 32);
                *(uint64_t*)(wbase + (ot * 4 + rq) * 1024 + bt * 512) = u;
            }
        }
    }
}

// One H->H layer: wave tile 128 o-cols x 64 b-rows, 32x32x16 MFMA, K=512.
// Rotation-free depth-2 pipeline: even steps use/refill aA, odd steps aB.
// The refill of a set is ordered after the MFMAs that read it (WAR) -> loads
// sit exactly 2 iterations (~512+ cyc) ahead of their consumers, no v_movs.
// aP seeds aA for ks=0 (issued before the preceding barrier).
template<bool USEWS>
__device__ __forceinline__ void layerH32(f32x16 (&acc)[4][2], const h16x8 (&aP)[4],
                                         const h16* __restrict__ wpk, const float* __restrict__ wf,
                                         const char* __restrict__ hb, int wv, int ln) {
    const int l31 = ln & 31, lh = ln >> 5;
    const char* const bbase = hb + l31 * 16 + lh * 1024;
    const int nb0 = wv * 4;
    #pragma unroll
    for (int ot = 0; ot < 4; ++ot)
        #pragma unroll
        for (int bt = 0; bt < 2; ++bt) acc[ot][bt] = (f32x16)(0.f);

    h16x8 aA[4], aB[4];
    #pragma unroll
    for (int ot = 0; ot < 4; ++ot) aA[ot] = aP[ot];
    #pragma unroll
    for (int ot = 0; ot < 4; ++ot)
        aB[ot] = loadA32ks<USEWS>(wpk, wf, 1, nb0 + ot, ln, H_);

    #pragma unroll 2
    for (int ks = 0; ks < 32; ks += 2) {
        // even step: consume aA (ks), refill aA for ks+2
        {
            const h16x8 b0 = *(const h16x8*)(bbase + ks * 2048);
            const h16x8 b1 = *(const h16x8*)(bbase + ks * 2048 + 512);
            __builtin_amdgcn_s_setprio(1);
            #pragma unroll
            for (int ot = 0; ot < 4; ++ot) {
                acc[ot][0] = __builtin_amdgcn_mfma_f32_32x32x16_f16(aA[ot], b0, acc[ot][0], 0, 0, 0);
                acc[ot][1] = __builtin_amdgcn_mfma_f32_32x32x16_f16(aA[ot], b1, acc[ot][1], 0, 0, 0);
            }
            __builtin_amdgcn_s_setprio(0);
            const int ksA = (ks + 2 < 32) ? ks + 2 : 0;   // clamped dummy at tail
            #pragma unroll
            for (int ot = 0; ot < 4; ++ot)
                aA[ot] = loadA32ks<USEWS>(wpk, wf, ksA, nb0 + ot, ln, H_);
        }
        // odd step: consume aB (ks+1), refill aB for ks+3
        {
            const h16x8 b0 = *(const h16x8*)(bbase + (ks + 1) * 2048);
            const h16x8 b1 = *(const h16x8*)(bbase + (ks + 1) * 2048 + 512);
            __builtin_amdgcn_s_setprio(1);
            #pragma unroll
            for (int ot = 0; ot < 4; ++ot) {
                acc[ot][0] = __builtin_amdgcn_mfma_f32_32x32x16_f16(aB[ot], b0, acc[ot][0], 0, 0, 0);
                acc[ot][1] = __builtin_amdgcn_mfma_f32_32x32x16_f16(aB[ot], b1, acc[ot][1], 0, 0, 0);
            }
            __builtin_amdgcn_s_setprio(0);
            const int ksB = (ks + 3 < 32) ? ks + 3 : 0;   // clamped dummy at tail
            #pragma unroll
            for (int ot = 0; ot < 4; ++ot)
                aB[ot] = loadA32ks<USEWS>(wpk, wf, ksB, nb0 + ot, ln, H_);
        }
    }
}

template<bool USEWS>
__device__ __forceinline__ void prefA(h16x8 (&aP)[4],
                                      const h16* __restrict__ wpk, const float* __restrict__ wf,
                                      int wv, int ln) {
    #pragma unroll
    for (int ot = 0; ot < 4; ++ot)
        aP[ot] = loadA32ks<USEWS>(wpk, wf, 0, wv * 4 + ot, ln, H_);
}

template<bool USEWS>
__global__ __launch_bounds__(NTH, 2) void mlp_fused(
    const float* __restrict__ x,
    const float* __restrict__ W1f, const float* __restrict__ b1, const float* __restrict__ be1,
    const float* __restrict__ W2f, const float* __restrict__ b2, const float* __restrict__ be2,
    const float* __restrict__ W3f, const float* __restrict__ b3, const float* __restrict__ be3,
    const float* __restrict__ W4f, const float* __restrict__ b4,
    const h16* __restrict__ W1p, const h16* __restrict__ W2p,
    const h16* __restrict__ W3p, const h16* __restrict__ W4p,
    float* __restrict__ out) {
    extern __shared__ char smem[];
    char* __restrict__ xb = smem + HB_BYTES;   // k-major x tile, 2 KB

    const int bid = blockIdx.x;
    const int g = bid & 7;                 // group == XCD; co-resident blocks share weights in L2
    const int rowbase = (bid >> 3) * TB;
    const int tid = threadIdx.x;
    const int wv = tid >> 6;               // 4 waves, wave wv owns cols 128wv..128wv+128
    const int ln = tid & 63;
    const int l31 = ln & 31;
    const int lh = ln >> 5;

    // spl = softplus(beta) * log2(e); swish folds /1.1 into the rcp argument.
    const float spl1 = log1pf(__expf(be1[g])) * 1.44269504f;
    const float spl2 = log1pf(__expf(be2[g])) * 1.44269504f;
    const float spl3 = log1pf(__expf(be3[g])) * 1.44269504f;

    const h16* w1p = W1p + (size_t)g * H_ * S_;
    const h16* w2p = W2p + (size_t)g * H_ * H_;
    const h16* w3p = W3p + (size_t)g * H_ * H_;
    const h16* w4p = W4p + (size_t)g * S_ * H_;
    const float* w1f = W1f + (size_t)g * H_ * S_;
    const float* w2f = W2f + (size_t)g * H_ * H_;
    const float* w3f = W3f + (size_t)g * H_ * H_;
    const float* w4f = W4f + (size_t)g * S_ * H_;

    // stage x tile -> fp16, k-major: (row r, chan s) -> (s>>3)*1024 + r*16 + (s&7)*2
    {
        const int idx = tid * 4;                         // 64*16 = 1024 h16, 4/thread
        const int r = idx >> 4, s = idx & 15;            // s in {0,4,8,12}
        const f32x4 v = *(const f32x4*)(x + (size_t)(rowbase + r) * (G_ * S_) + g * S_ + s);
        const uint64_t u = (uint64_t)pk16(v[0], v[1]) | ((uint64_t)pk16(v[2], v[3]) << 32);
        *(uint64_t*)(xb + (s >> 3) * 1024 + r * 16 + (s & 7) * 2) = u;
    }
    __syncthreads();

    f32x16 acc[4][2];
    h16x8 aP[4];

    // ---- layer 1: A=W1[512,16] frags, B=x frags (k-major), single K-step ----
    {
        #pragma unroll
        for (int ot = 0; ot < 4; ++ot)
            #pragma unroll
            for (int bt = 0; bt < 2; ++bt) acc[ot][bt] = (f32x16)(0.f);
        const char* const xbase = xb + l31 * 16 + lh * 1024;
        const h16x8 bX0 = *(const h16x8*)(xbase);
        const h16x8 bX1 = *(const h16x8*)(xbase + 512);
        #pragma unroll
        for (int ot = 0; ot < 4; ++ot) {
            const h16x8 aW = loadA32ks<USEWS>(w1p, w1f, 0, wv * 4 + ot, ln, S_);
            acc[ot][0] = __builtin_amdgcn_mfma_f32_32x32x16_f16(aW, bX0, acc[ot][0], 0, 0, 0);
            acc[ot][1] = __builtin_amdgcn_mfma_f32_32x32x16_f16(aW, bX1, acc[ot][1], 0, 0, 0);
        }
    }
    prefA<USEWS>(aP, w2p, w2f, wv, ln);    // layer-2 ks=0 frags: latency hides under store
    swish_store32(acc, smem, b1 + g * H_, spl1, wv, ln);
    __syncthreads();

    // ---- layer 2 ----
    layerH32<USEWS>(acc, aP, w2p, w2f, smem, wv, ln);
    __syncthreads();                       // all hbuf reads done
    prefA<USEWS>(aP, w3p, w3f, wv, ln);    // layer-3 ks=0 frags
    swish_store32(acc, smem, b2 + g * H_, spl2, wv, ln);
    __syncthreads();

    // ---- layer 3 ----
    layerH32<USEWS>(acc, aP, w3p, w3f, smem, wv, ln);
    __syncthreads();
    swish_store32(acc, smem, b3 + g * H_, spl3, wv, ln);
    __syncthreads();

    // ---- layer 4: A=W4[16,512] frags (16x16x32), B=act k-major; 4 waves x 16 rows ----
    {
        f32x4 a4 = {0.f, 0.f, 0.f, 0.f};
        const int l15 = ln & 15, lq = ln >> 4;
        // B-frag: row = wv*16+l15, k = ks*32 + lq*8 -> byte = (ks*4+lq)*1024 + row*16
        const char* const b4base = smem + lq * 1024 + (wv * 16 + l15) * 16;
        #pragma unroll 4
        for (int ks = 0; ks < 16; ++ks) {
            const h16x8 a = loadA16<USEWS>(w4p, w4f, ks, ln, H_);
            const h16x8 b = *(const h16x8*)(b4base + ks * 4096);
            a4 = __builtin_amdgcn_mfma_f32_16x16x32_f16(a, b, a4, 0, 0, 0);
        }
        const int brow = wv * 16 + l15;    // batch row
        const int s0 = lq * 4;             // 4 consecutive state channels
        const f32x4 bv = *(const f32x4*)(b4 + g * S_ + s0);
        f32x4 o4;
        #pragma unroll
        for (int r = 0; r < 4; ++r) o4[r] = a4[r] + bv[r];
        *(f32x4*)(out + (size_t)(rowbase + brow) * (G_ * S_) + g * S_ + s0) = o4;
    }
}

// ---- weight repack (32x32x16, ks-major): fp32 [G*N][Ks] -> per-group [ks][nb][64][8] ----
__global__ void packW32(const float* __restrict__ s, h16* __restrict__ d,
                        int KB, int Ks) {
    const int t = blockIdx.x * 256 + threadIdx.x;
    const int total = G_ * KB * 16 * 64;
    if (t >= total) return;
    const int ln = t & 63;
    const int blk = t >> 6;                // ((g*KB + ks)*16 + nb)
    const int nb = blk & 15;
    const int rest = blk >> 4;
    const int ks = rest % KB;
    const int g = rest / KB;
    const int row = g * H_ + nb * 32 + (ln & 31);
    const int k = ks * 16 + (ln >> 5) * 8;
    const float* p = s + (size_t)row * Ks + k;
    h16x8 o;
    #pragma unroll
    for (int j = 0; j < 8; ++j) o[j] = (h16)p[j];
    *(h16x8*)(d + (size_t)t * 8) = o;
}

// ---- weight repack (16x16x32, W4): fp32 [G*16][512] -> per-group [ks][64][8] ----
__global__ void packW16(const float* __restrict__ s, h16* __restrict__ d,
                        int NB_total, int KB, int Ks) {
    const int t = blockIdx.x * 256 + threadIdx.x;
    const int total = NB_total * KB * 64;
    if (t >= total) return;
    const int ln = t & 63;
    const int blk = t >> 6;
    const int kb = blk % KB;
    const int nbg = blk / KB;
    const int row = nbg * 16 + (ln & 15);
    const int k = kb * 32 + (ln >> 4) * 8;
    const float* p = s + (size_t)row * Ks + k;
    h16x8 o;
    #pragma unroll
    for (int j = 0; j < 8; ++j) o[j] = (h16)p[j];
    *(h16x8*)(d + (size_t)t * 8) = o;
}

extern "C" void kernel_launch(void* const* d_in, const int* in_sizes, int n_in,
                              void* d_out, int out_size, void* d_ws, size_t ws_size,
                              hipStream_t stream) {
    const float* x   = (const float*)d_in[0];
    const float* W1  = (const float*)d_in[1];
    const float* b1  = (const float*)d_in[2];
    const float* be1 = (const float*)d_in[3];
    const float* W2  = (const float*)d_in[4];
    const float* b2  = (const float*)d_in[5];
    const float* be2 = (const float*)d_in[6];
    const float* W3  = (const float*)d_in[7];
    const float* b3  = (const float*)d_in[8];
    const float* be3 = (const float*)d_in[9];
    const float* W4  = (const float*)d_in[10];
    const float* b4  = (const float*)d_in[11];
    float* out = (float*)d_out;

    const size_t nW2  = (size_t)G_ * H_ * H_;   // 2097152
    const size_t nW1p = (size_t)G_ * H_ * S_;   // 65536
    const size_t nW4  = (size_t)G_ * S_ * H_;   // 65536
    const size_t need = (2 * nW2 + nW1p + nW4) * sizeof(h16);

    const dim3 grid((16384 / TB) * G_), blk(NTH);   // 2048 blocks x 256 thr

    if (ws_size >= need) {
        h16* W2p = (h16*)d_ws;
        h16* W3p = W2p + nW2;
        h16* W1p = W3p + nW2;
        h16* W4p = W1p + nW1p;
        packW32<<<dim3((unsigned)((nW2 / 8 + 255) / 256)), dim3(256), 0, stream>>>(W2, W2p, 32, H_);
        packW32<<<dim3((unsigned)((nW2 / 8 + 255) / 256)), dim3(256), 0, stream>>>(W3, W3p, 32, H_);
        packW32<<<dim3((unsigned)((nW1p / 8 + 255) / 256)), dim3(256), 0, stream>>>(W1, W1p, 1, S_);
        packW16<<<dim3((unsigned)((nW4 / 8 + 255) / 256)), dim3(256), 0, stream>>>(W4, W4p, G_, 16, H_);
        (void)hipFuncSetAttribute(reinterpret_cast<const void*>(mlp_fused<true>),
                                  hipFuncAttributeMaxDynamicSharedMemorySize, (int)SMEM_BYTES);
        mlp_fused<true><<<grid, blk, SMEM_BYTES, stream>>>(
            x, W1, b1, be1, W2, b2, be2, W3, b3, be3, W4, b4,
            W1p, W2p, W3p, W4p, out);
    } else {
        (void)hipFuncSetAttribute(reinterpret_cast<const void*>(mlp_fused<false>),
                                  hipFuncAttributeMaxDynamicSharedMemorySize, (int)SMEM_BYTES);
        mlp_fused<false><<<grid, blk, SMEM_BYTES, stream>>>(
            x, W1, b1, be1, W2, b2, be2, W3, b3, be3, W4, b4,
            nullptr, nullptr, nullptr, nullptr, out);
    }
}